// Round 4
// baseline (422.283 us; speedup 1.0000x reference)
//
#include <hip/hip_runtime.h>

#define CIN 32
#define COUT 64

typedef __attribute__((ext_vector_type(8))) short bf16x8;
typedef __attribute__((ext_vector_type(4))) float f32x4;

__device__ inline short bf16r(float x) {
    unsigned u = __float_as_uint(x);
    return (short)((u + 0x7FFFu + ((u >> 16) & 1u)) >> 16);
}

// ---------------------------------------------------------------------------
// Pack W1 (35x64, K zero-padded to 64) and W2 (64x64) into per-lane MFMA
// B-fragments for mfma_f32_16x16x32_bf16 (layout verified in R3).
__global__ void pack_weights_kernel(const float* __restrict__ W1,
                                    const float* __restrict__ W2,
                                    short* __restrict__ wpack) {
    int t = blockIdx.x * blockDim.x + threadIdx.x;   // 16*64*8 = 8192
    if (t >= 16 * 64 * 8) return;
    int e = t & 7, l = (t >> 3) & 63, f = t >> 9;
    int g = l >> 4, n16 = l & 15;
    int kc = (f & 7) >> 2, nt = f & 3;
    int k = kc * 32 + g * 8 + e;
    int n = nt * 16 + n16;
    float v;
    if (f < 8) v = (k < CIN + 3) ? W1[k * COUT + n] : 0.f;
    else       v = W2[k * COUT + n];
    wpack[t] = bf16r(v);
}

// ---------------------------------------------------------------------------
__global__ void gather_bxyz_kernel(const float4* __restrict__ bxyz4,
                                   const int* __restrict__ sidx,
                                   float4* __restrict__ out4, int M) {
    int i = blockIdx.x * blockDim.x + threadIdx.x;
    if (i < M) out4[i] = bxyz4[sidx[i]];
}

// ---------------------------------------------------------------------------
// CSR build: zero -> histogram -> scan (3 kernels) -> scatter e_point values.
__global__ void zero_counts_kernel(int* __restrict__ counts, int M) {
    int i = blockIdx.x * blockDim.x + threadIdx.x;
    if (i < M) counts[i] = 0;
}

__global__ void hist_kernel(const int* __restrict__ e_new,
                            int* __restrict__ counts, int E) {
    int e = blockIdx.x * blockDim.x + threadIdx.x;
    if (e < E) atomicAdd(&counts[e_new[e]], 1);
}

#define SCHUNK 1024   // elements per scan block (256 thr x 4)

__global__ void scanA_kernel(const int* __restrict__ counts,
                             int* __restrict__ row1,   // = row_start + 1
                             int* __restrict__ sums, int M) {
    __shared__ int lds[256];
    int t = threadIdx.x, blk = blockIdx.x;
    int base = blk * SCHUNK + t * 4;
    int v0 = (base + 0 < M) ? counts[base + 0] : 0;
    int v1 = (base + 1 < M) ? counts[base + 1] : 0;
    int v2 = (base + 2 < M) ? counts[base + 2] : 0;
    int v3 = (base + 3 < M) ? counts[base + 3] : 0;
    int s = v0 + v1 + v2 + v3;
    int val = s;
    lds[t] = val; __syncthreads();
    for (int off = 1; off < 256; off <<= 1) {
        int x = (t >= off) ? lds[t - off] : 0;
        __syncthreads();
        val += x; lds[t] = val;
        __syncthreads();
    }
    int ex = val - s;
    if (base + 0 < M) row1[base + 0] = ex + v0;
    if (base + 1 < M) row1[base + 1] = ex + v0 + v1;
    if (base + 2 < M) row1[base + 2] = ex + v0 + v1 + v2;
    if (base + 3 < M) row1[base + 3] = ex + s;
    if (t == 255) sums[blk] = val;
}

__global__ void scanB_kernel(int* __restrict__ sums, int n) {
    __shared__ int lds[256];
    int t = threadIdx.x;
    int s = (t < n) ? sums[t] : 0;
    int val = s;
    lds[t] = val; __syncthreads();
    for (int off = 1; off < 256; off <<= 1) {
        int x = (t >= off) ? lds[t - off] : 0;
        __syncthreads();
        val += x; lds[t] = val;
        __syncthreads();
    }
    if (t < n) sums[t] = val;   // inclusive
}

__global__ void scanC_kernel(int* __restrict__ row1,
                             const int* __restrict__ sums,
                             int* __restrict__ row_start, int M) {
    int blk = blockIdx.x, t = threadIdx.x;
    if (blk == 0) {
        if (t == 0) row_start[0] = 0;
        return;
    }
    int off = sums[blk - 1];
    int base = blk * SCHUNK + t * 4;
#pragma unroll
    for (int i = 0; i < 4; ++i)
        if (base + i < M) row1[base + i] += off;
}

__global__ void scatter_kernel(const int* __restrict__ e_new,
                               const int* __restrict__ e_point,
                               const int* __restrict__ row_start,
                               int* __restrict__ counts,   // destroyed
                               int* __restrict__ csr_ep, int E) {
    int e = blockIdx.x * blockDim.x + threadIdx.x;
    if (e >= E) return;
    int seg = e_new[e];
    int old = atomicSub(&counts[seg], 1);
    csr_ep[row_start[seg] + old - 1] = e_point[e];
}

// ---------------------------------------------------------------------------
// Aggregation: wave = segment. Gather the segment's edges (16 per MFMA tile),
// MLP via MFMA (layouts verified R3), max over rows in-register, one coalesced
// 256B row store per segment. No atomics, no pre-check reads, no zero-init.
__global__ __launch_bounds__(256)
void agg_kernel(const float4* __restrict__ bxyz4,
                const float* __restrict__ feat,
                const int* __restrict__ csr_ep,
                const int* __restrict__ row_start,
                const bf16x8* __restrict__ wpack,
                const float* __restrict__ b1,
                const float* __restrict__ b2,
                const float4* __restrict__ new_bxyz4,
                float* __restrict__ out_feat, int M) {
    __shared__ char h1buf[4][2048];   // wave-private, XOR-swizzled
    const int lane = threadIdx.x & 63;
    const int w    = threadIdx.x >> 6;
    const int m    = lane & 15;
    const int g    = lane >> 4;

    int seg = blockIdx.x * 4 + w;
    if (seg >= M) return;             // wave-uniform, no barriers used

    bf16x8 w1b[8], w2b[8];
#pragma unroll
    for (int f = 0; f < 8; ++f) w1b[f] = wpack[f * 64 + lane];
#pragma unroll
    for (int f = 0; f < 8; ++f) w2b[f] = wpack[(8 + f) * 64 + lane];

    float b1v[4], b2v[4];
#pragma unroll
    for (int nt = 0; nt < 4; ++nt) {
        b1v[nt] = b1[nt * 16 + m];
        b2v[nt] = b2[nt * 16 + m];
    }

    int r0 = row_start[seg];
    int r1 = row_start[seg + 1];
    float4 nb = new_bxyz4[seg];
    char* h1p = h1buf[w];

    f32x4 accv = {0.f, 0.f, 0.f, 0.f};   // init 0 == relu floor == empty-seg value

    for (int c = r0; c < r1; c += 16) {
        int i = min(c + m, r1 - 1);        // clamp -> duplicate edges, max-safe
        int ep = csr_ep[i];

        const float4* fp = (const float4*)(feat + (size_t)ep * CIN);
        float4 f0 = fp[g * 2];
        float4 f1 = fp[g * 2 + 1];

        bf16x8 a1;
        a1[0] = bf16r(f0.x); a1[1] = bf16r(f0.y); a1[2] = bf16r(f0.z); a1[3] = bf16r(f0.w);
        a1[4] = bf16r(f1.x); a1[5] = bf16r(f1.y); a1[6] = bf16r(f1.z); a1[7] = bf16r(f1.w);

        bf16x8 a2 = {0, 0, 0, 0, 0, 0, 0, 0};
        if (g == 0) {
            float4 pb = bxyz4[ep];
            a2[0] = bf16r(pb.y - nb.y);
            a2[1] = bf16r(pb.z - nb.z);
            a2[2] = bf16r(pb.w - nb.w);
        }

        // ---- layer 1 ------------------------------------------------------
        f32x4 acc[4];
#pragma unroll
        for (int nt = 0; nt < 4; ++nt) {
            f32x4 cc = {b1v[nt], b1v[nt], b1v[nt], b1v[nt]};
            cc = __builtin_amdgcn_mfma_f32_16x16x32_bf16(a1, w1b[nt],     cc, 0, 0, 0);
            cc = __builtin_amdgcn_mfma_f32_16x16x32_bf16(a2, w1b[4 + nt], cc, 0, 0, 0);
            acc[nt] = cc;
        }

        // ---- relu + transpose through wave-private LDS --------------------
#pragma unroll
        for (int nt = 0; nt < 4; ++nt)
#pragma unroll
            for (int q = 0; q < 4; ++q) {
                int row = g * 4 + q;
                int col = m + nt * 16;
                float h = fmaxf(acc[nt][q], 0.f);
                int byte = (row * 128 + col * 2) ^ ((row & 7) << 4);
                *(short*)(h1p + byte) = bf16r(h);
            }

        bf16x8 a30 = *(const bf16x8*)(h1p + ((m * 128 + g * 16)       ^ ((m & 7) << 4)));
        bf16x8 a31 = *(const bf16x8*)(h1p + ((m * 128 + (4 + g) * 16) ^ ((m & 7) << 4)));

        // ---- layer 2 ------------------------------------------------------
        f32x4 acc2[4];
#pragma unroll
        for (int nt = 0; nt < 4; ++nt) {
            f32x4 cc = {b2v[nt], b2v[nt], b2v[nt], b2v[nt]};
            cc = __builtin_amdgcn_mfma_f32_16x16x32_bf16(a30, w2b[nt],     cc, 0, 0, 0);
            cc = __builtin_amdgcn_mfma_f32_16x16x32_bf16(a31, w2b[4 + nt], cc, 0, 0, 0);
            acc2[nt] = cc;
        }

        // ---- max over the 4 rows held in-lane -----------------------------
#pragma unroll
        for (int nt = 0; nt < 4; ++nt) {
            f32x4 c2 = acc2[nt];
            float t = fmaxf(fmaxf(c2[0], c2[1]), fmaxf(c2[2], c2[3]));
            accv[nt] = fmaxf(accv[nt], t);
        }
    }

    // ---- max across the 4 row-groups (lanes m, m+16, m+32, m+48) ----------
#pragma unroll
    for (int nt = 0; nt < 4; ++nt) {
        float v = accv[nt];
        v = fmaxf(v, __shfl_xor(v, 16));
        v = fmaxf(v, __shfl_xor(v, 32));
        accv[nt] = v;
    }
    // lane (g,m) owns channel n = g*16 + m == lane  -> coalesced 256B row
    float outv = (g == 0) ? accv[0] : (g == 1) ? accv[1] : (g == 2) ? accv[2] : accv[3];
    out_feat[(size_t)seg * COUT + lane] = outv;
}

// ---------------------------------------------------------------------------
extern "C" void kernel_launch(void* const* d_in, const int* in_sizes, int n_in,
                              void* d_out, int out_size, void* d_ws, size_t ws_size,
                              hipStream_t stream) {
    const float* bxyz   = (const float*)d_in[0];
    const float* feat   = (const float*)d_in[1];
    const int*   sidx   = (const int*)d_in[2];
    const int*   e_pt   = (const int*)d_in[3];
    const int*   e_new  = (const int*)d_in[4];
    const float* W1     = (const float*)d_in[5];
    const float* b1     = (const float*)d_in[6];
    const float* W2     = (const float*)d_in[7];
    const float* b2     = (const float*)d_in[8];

    const int M = in_sizes[2];
    const int E = in_sizes[3];

    float* out_bxyz = (float*)d_out;                 // [M][4]
    float* out_feat = out_bxyz + (size_t)M * 4;      // [M][64]

    // ws layout
    char* ws = (char*)d_ws;
    short* wpack     = (short*)ws;                               // 16384 B
    int*   counts    = (int*)(ws + 16384);                       // M ints
    int*   row_start = (int*)(ws + 16384 + (size_t)M * 4);       // M+1 ints
    int*   sums      = (int*)(ws + 16384 + (size_t)(2 * M + 1) * 4);      // scan chunk sums
    int*   csr_ep    = (int*)(ws + 16384 + (size_t)(2 * M + 1) * 4 + 2048);  // E ints
    int*   row1      = row_start + 1;

    int nchunks = (M + SCHUNK - 1) / SCHUNK;

    pack_weights_kernel<<<32, 256, 0, stream>>>(W1, W2, wpack);

    gather_bxyz_kernel<<<(M + 255) / 256, 256, 0, stream>>>(
        (const float4*)bxyz, sidx, (float4*)out_bxyz, M);

    zero_counts_kernel<<<(M + 255) / 256, 256, 0, stream>>>(counts, M);
    hist_kernel<<<(E + 255) / 256, 256, 0, stream>>>(e_new, counts, E);
    scanA_kernel<<<nchunks, 256, 0, stream>>>(counts, row1, sums, M);
    scanB_kernel<<<1, 256, 0, stream>>>(sums, nchunks);
    scanC_kernel<<<nchunks, 256, 0, stream>>>(row1, sums, row_start, M);
    scatter_kernel<<<(E + 255) / 256, 256, 0, stream>>>(
        e_new, e_pt, row_start, counts, csr_ep, E);

    agg_kernel<<<(M + 3) / 4, 256, 0, stream>>>(
        (const float4*)bxyz, feat, csr_ep, row_start,
        (const bf16x8*)wpack, b1, b2,
        (const float4*)out_bxyz, out_feat, M);
}

// Round 5
// 415.958 us; speedup vs baseline: 1.0152x; 1.0152x over previous
//
#include <hip/hip_runtime.h>
#include <hip/hip_bf16.h>

#define CIN 32
#define COUT 64
#define SEGS 4
#define SCHUNK 1024

typedef __attribute__((ext_vector_type(8))) short bf16x8;
typedef __attribute__((ext_vector_type(4))) float f32x4;

__device__ inline short bf16r(float x) {
    unsigned u = __float_as_uint(x);
    return (short)((u + 0x7FFFu + ((u >> 16) & 1u)) >> 16);
}

__device__ inline unsigned pk2(float lo, float hi) {
    __hip_bfloat162 t = __float22bfloat162_rn(make_float2(lo, hi));
    return *(unsigned*)&t;
}

// ---------------------------------------------------------------------------
// Fused prep: [0,32) pack weights | [32,32+nbm) gather bxyz | [.,+nbm) zero
// counts | rest: feat f32 -> bf16 (8 elems/thread).
__global__ void prep_kernel(const float* __restrict__ W1,
                            const float* __restrict__ W2,
                            short* __restrict__ wpack,
                            const float4* __restrict__ bxyz4,
                            const int* __restrict__ sidx,
                            float4* __restrict__ out_bxyz,
                            int* __restrict__ counts,
                            const float* __restrict__ feat,
                            uint4* __restrict__ featb,
                            int M, int N, int nbm) {
    int b = blockIdx.x, tid = threadIdx.x;
    if (b < 32) {
        int t = b * 256 + tid;                 // 8192 exactly
        int e = t & 7, l = (t >> 3) & 63, f = t >> 9;
        int g = l >> 4, n16 = l & 15;
        int kc = (f & 7) >> 2, nt = f & 3;
        int k = kc * 32 + g * 8 + e;
        int n = nt * 16 + n16;
        float v;
        if (f < 8) v = (k < CIN + 3) ? W1[k * COUT + n] : 0.f;
        else       v = W2[k * COUT + n];
        wpack[t] = bf16r(v);
    } else if (b < 32 + nbm) {
        int i = (b - 32) * 256 + tid;
        if (i < M) out_bxyz[i] = bxyz4[sidx[i]];
    } else if (b < 32 + 2 * nbm) {
        int i = (b - 32 - nbm) * 256 + tid;
        if (i < M) counts[i] = 0;
    } else {
        int i = (b - 32 - 2 * nbm) * 256 + tid;   // i indexes 8-float chunks
        if (i < N * (CIN / 8)) {
            const float4* s = (const float4*)feat + (size_t)i * 2;
            float4 a = s[0], c = s[1];
            uint4 o;
            o.x = pk2(a.x, a.y); o.y = pk2(a.z, a.w);
            o.z = pk2(c.x, c.y); o.w = pk2(c.z, c.w);
            featb[i] = o;
        }
    }
}

// ---------------------------------------------------------------------------
__global__ void hist_kernel(const int4* __restrict__ e_new4,
                            int* __restrict__ counts, int E4) {
    int i = blockIdx.x * blockDim.x + threadIdx.x;
    if (i < E4) {
        int4 v = e_new4[i];
        atomicAdd(&counts[v.x], 1);
        atomicAdd(&counts[v.y], 1);
        atomicAdd(&counts[v.z], 1);
        atomicAdd(&counts[v.w], 1);
    }
}

__global__ void scanA_kernel(const int* __restrict__ counts,
                             int* __restrict__ row1,
                             int* __restrict__ sums, int M) {
    __shared__ int lds[256];
    int t = threadIdx.x, blk = blockIdx.x;
    int base = blk * SCHUNK + t * 4;
    int v0 = (base + 0 < M) ? counts[base + 0] : 0;
    int v1 = (base + 1 < M) ? counts[base + 1] : 0;
    int v2 = (base + 2 < M) ? counts[base + 2] : 0;
    int v3 = (base + 3 < M) ? counts[base + 3] : 0;
    int s = v0 + v1 + v2 + v3;
    int val = s;
    lds[t] = val; __syncthreads();
    for (int off = 1; off < 256; off <<= 1) {
        int x = (t >= off) ? lds[t - off] : 0;
        __syncthreads();
        val += x; lds[t] = val;
        __syncthreads();
    }
    int ex = val - s;
    if (base + 0 < M) row1[base + 0] = ex + v0;
    if (base + 1 < M) row1[base + 1] = ex + v0 + v1;
    if (base + 2 < M) row1[base + 2] = ex + v0 + v1 + v2;
    if (base + 3 < M) row1[base + 3] = ex + s;
    if (t == 255) sums[blk] = val;
}

__global__ void scanB_kernel(int* __restrict__ sums, int n) {
    __shared__ int lds[256];
    int t = threadIdx.x;
    int s = (t < n) ? sums[t] : 0;
    int val = s;
    lds[t] = val; __syncthreads();
    for (int off = 1; off < 256; off <<= 1) {
        int x = (t >= off) ? lds[t - off] : 0;
        __syncthreads();
        val += x; lds[t] = val;
        __syncthreads();
    }
    if (t < n) sums[t] = val;
}

__global__ void scanC_kernel(int* __restrict__ row1,
                             const int* __restrict__ sums,
                             int* __restrict__ row_start, int M) {
    int blk = blockIdx.x, t = threadIdx.x;
    if (blk == 0) {
        if (t == 0) row_start[0] = 0;
        return;
    }
    int off = sums[blk - 1];
    int base = blk * SCHUNK + t * 4;
#pragma unroll
    for (int i = 0; i < 4; ++i)
        if (base + i < M) row1[base + i] += off;
}

__global__ void scatter_kernel(const int4* __restrict__ e_new4,
                               const int4* __restrict__ e_point4,
                               const int* __restrict__ row_start,
                               int* __restrict__ counts,
                               int* __restrict__ csr_ep, int E4) {
    int i = blockIdx.x * blockDim.x + threadIdx.x;
    if (i >= E4) return;
    int4 sn = e_new4[i];
    int4 sp = e_point4[i];
    int o0 = atomicSub(&counts[sn.x], 1);
    int o1 = atomicSub(&counts[sn.y], 1);
    int o2 = atomicSub(&counts[sn.z], 1);
    int o3 = atomicSub(&counts[sn.w], 1);
    csr_ep[row_start[sn.x] + o0 - 1] = sp.x;
    csr_ep[row_start[sn.y] + o1 - 1] = sp.y;
    csr_ep[row_start[sn.z] + o2 - 1] = sp.z;
    csr_ep[row_start[sn.w] + o3 - 1] = sp.w;
}

// ---------------------------------------------------------------------------
// Aggregation: wave = segment (SEGS per wave, grid-stride). MFMA MLP, f32 LDS
// transpose with XOR swizzle + cvt_pk on read, in-register max, coalesced
// row store. No atomics. BF: feat pre-converted to bf16 (16B A-frag load).
template <bool BF>
__global__ __launch_bounds__(256)
void agg_kernel(const float4* __restrict__ bxyz4,
                const float* __restrict__ feat,
                const bf16x8* __restrict__ featb,
                const int* __restrict__ csr_ep,
                const int* __restrict__ row_start,
                const bf16x8* __restrict__ wpack,
                const float* __restrict__ b1,
                const float* __restrict__ b2,
                const float4* __restrict__ new_bxyz4,
                float* __restrict__ out_feat, int M) {
    __shared__ char h1buf[4][4096];   // wave-private 16x64 f32, swizzled
    const int lane = threadIdx.x & 63;
    const int w    = threadIdx.x >> 6;
    const int m    = lane & 15;
    const int g    = lane >> 4;

    bf16x8 w1b[8], w2b[8];
#pragma unroll
    for (int f = 0; f < 8; ++f) w1b[f] = wpack[f * 64 + lane];
#pragma unroll
    for (int f = 0; f < 8; ++f) w2b[f] = wpack[(8 + f) * 64 + lane];

    float b1v[4], b2v[4];
#pragma unroll
    for (int nt = 0; nt < 4; ++nt) {
        b1v[nt] = b1[nt * 16 + m];
        b2v[nt] = b2[nt * 16 + m];
    }

    char* h1p = h1buf[w];
    int segbase = (blockIdx.x * 4 + w) * SEGS;

    for (int s = 0; s < SEGS; ++s) {
        int seg = segbase + s;                 // wave-uniform
        if (seg >= M) break;
        int r0 = row_start[seg];
        int r1 = row_start[seg + 1];
        float4 nb = new_bxyz4[seg];

        f32x4 accv = {0.f, 0.f, 0.f, 0.f};    // relu floor == empty-seg value

        for (int c = r0; c < r1; c += 16) {
            int i = min(c + m, r1 - 1);        // clamp: dup edges, max-safe
            int ep = csr_ep[i];

            bf16x8 a1;
            if constexpr (BF) {
                a1 = featb[(size_t)ep * 4 + g];          // one dwordx4
            } else {
                const float4* fp = (const float4*)(feat + (size_t)ep * CIN);
                float4 f0 = fp[g * 2];
                float4 f1 = fp[g * 2 + 1];
                union { bf16x8 v; unsigned u[4]; } U;
                U.u[0] = pk2(f0.x, f0.y); U.u[1] = pk2(f0.z, f0.w);
                U.u[2] = pk2(f1.x, f1.y); U.u[3] = pk2(f1.z, f1.w);
                a1 = U.v;
            }

            bf16x8 a2 = {0, 0, 0, 0, 0, 0, 0, 0};
            if (g == 0) {
                float4 pb = bxyz4[ep];
                a2[0] = bf16r(pb.y - nb.y);
                a2[1] = bf16r(pb.z - nb.z);
                a2[2] = bf16r(pb.w - nb.w);
            }

            // ---- layer 1 --------------------------------------------------
            f32x4 acc[4];
#pragma unroll
            for (int nt = 0; nt < 4; ++nt) {
                f32x4 cc = {b1v[nt], b1v[nt], b1v[nt], b1v[nt]};
                cc = __builtin_amdgcn_mfma_f32_16x16x32_bf16(a1, w1b[nt],     cc, 0, 0, 0);
                cc = __builtin_amdgcn_mfma_f32_16x16x32_bf16(a2, w1b[4 + nt], cc, 0, 0, 0);
                acc[nt] = cc;
            }

            // ---- relu + f32 transpose through wave-private LDS ------------
#pragma unroll
            for (int nt = 0; nt < 4; ++nt)
#pragma unroll
                for (int q = 0; q < 4; ++q) {
                    int row = g * 4 + q;
                    int col = m + nt * 16;
                    float h = fmaxf(acc[nt][q], 0.f);
                    int byte = (row * 256 + col * 4) ^ ((row & 7) << 5);
                    *(float*)(h1p + byte) = h;
                }

            // read back edge-row m, channels g*8..g*8+7 (+32 for a31)
            const int key = (m & 7) << 5;
            float4 q0 = *(const float4*)(h1p + ((m * 256 + g * 32)        ^ key));
            float4 q1 = *(const float4*)(h1p + ((m * 256 + g * 32 + 16)   ^ key));
            float4 q2 = *(const float4*)(h1p + ((m * 256 + 128 + g * 32)      ^ key));
            float4 q3 = *(const float4*)(h1p + ((m * 256 + 128 + g * 32 + 16) ^ key));

            union { bf16x8 v; unsigned u[4]; } A30, A31;
            A30.u[0] = pk2(q0.x, q0.y); A30.u[1] = pk2(q0.z, q0.w);
            A30.u[2] = pk2(q1.x, q1.y); A30.u[3] = pk2(q1.z, q1.w);
            A31.u[0] = pk2(q2.x, q2.y); A31.u[1] = pk2(q2.z, q2.w);
            A31.u[2] = pk2(q3.x, q3.y); A31.u[3] = pk2(q3.z, q3.w);

            // ---- layer 2 --------------------------------------------------
            f32x4 acc2[4];
#pragma unroll
            for (int nt = 0; nt < 4; ++nt) {
                f32x4 cc = {b2v[nt], b2v[nt], b2v[nt], b2v[nt]};
                cc = __builtin_amdgcn_mfma_f32_16x16x32_bf16(A30.v, w2b[nt],     cc, 0, 0, 0);
                cc = __builtin_amdgcn_mfma_f32_16x16x32_bf16(A31.v, w2b[4 + nt], cc, 0, 0, 0);
                acc2[nt] = cc;
            }

            // ---- max over the 4 rows held in-lane -------------------------
#pragma unroll
            for (int nt = 0; nt < 4; ++nt) {
                f32x4 c2 = acc2[nt];
                float t = fmaxf(fmaxf(c2[0], c2[1]), fmaxf(c2[2], c2[3]));
                accv[nt] = fmaxf(accv[nt], t);
            }
        }

        // ---- max across row-groups + coalesced store ----------------------
#pragma unroll
        for (int nt = 0; nt < 4; ++nt) {
            float v = accv[nt];
            v = fmaxf(v, __shfl_xor(v, 16));
            v = fmaxf(v, __shfl_xor(v, 32));
            accv[nt] = v;
        }
        float outv = (g == 0) ? accv[0] : (g == 1) ? accv[1]
                   : (g == 2) ? accv[2] : accv[3];
        out_feat[(size_t)seg * COUT + lane] = outv;
    }
}

// ---------------------------------------------------------------------------
extern "C" void kernel_launch(void* const* d_in, const int* in_sizes, int n_in,
                              void* d_out, int out_size, void* d_ws, size_t ws_size,
                              hipStream_t stream) {
    const float* bxyz   = (const float*)d_in[0];
    const float* feat   = (const float*)d_in[1];
    const int*   sidx   = (const int*)d_in[2];
    const int*   e_pt   = (const int*)d_in[3];
    const int*   e_new  = (const int*)d_in[4];
    const float* W1     = (const float*)d_in[5];
    const float* b1     = (const float*)d_in[6];
    const float* W2     = (const float*)d_in[7];
    const float* b2     = (const float*)d_in[8];

    const int N = in_sizes[0] / 4;
    const int M = in_sizes[2];
    const int E = in_sizes[3];

    float* out_bxyz = (float*)d_out;                 // [M][4]
    float* out_feat = out_bxyz + (size_t)M * 4;      // [M][64]

    // ws layout (16B aligned regions)
    char*  ws        = (char*)d_ws;
    short* wpack     = (short*)ws;                                    // 16 KiB
    size_t off_cnt   = 16384;
    int*   counts    = (int*)(ws + off_cnt);                          // M
    size_t off_row   = off_cnt + (size_t)M * 4;
    int*   row_start = (int*)(ws + off_row);                          // M+4
    size_t off_sums  = off_row + ((size_t)M + 4) * 4;
    int*   sums      = (int*)(ws + off_sums);                         // 256
    size_t off_csr   = off_sums + 1024;
    int*   csr_ep    = (int*)(ws + off_csr);                          // E
    size_t off_fb    = (off_csr + (size_t)E * 4 + 15) & ~(size_t)15;
    uint4* featb     = (uint4*)(ws + off_fb);                         // N*64B
    size_t need_bf   = off_fb + (size_t)N * CIN * 2;
    int*   row1      = row_start + 1;

    const bool use_bf = ws_size >= need_bf;

    int nbm     = (M + 255) / 256;
    int nbfeat  = use_bf ? (N * (CIN / 8) + 255) / 256 : 0;
    int nchunks = (M + SCHUNK - 1) / SCHUNK;
    int E4      = E / 4;   // E divisible by 4 here

    prep_kernel<<<32 + 2 * nbm + nbfeat, 256, 0, stream>>>(
        W1, W2, wpack, (const float4*)bxyz, sidx, (float4*)out_bxyz,
        counts, feat, featb, M, N, nbm);

    hist_kernel<<<(E4 + 255) / 256, 256, 0, stream>>>(
        (const int4*)e_new, counts, E4);
    scanA_kernel<<<nchunks, 256, 0, stream>>>(counts, row1, sums, M);
    scanB_kernel<<<1, 256, 0, stream>>>(sums, nchunks);
    scanC_kernel<<<nchunks, 256, 0, stream>>>(row1, sums, row_start, M);
    scatter_kernel<<<(E4 + 255) / 256, 256, 0, stream>>>(
        (const int4*)e_new, (const int4*)e_pt, row_start, counts, csr_ep, E4);

    int nblocks = (M + SEGS * 4 - 1) / (SEGS * 4);
    if (use_bf)
        agg_kernel<true><<<nblocks, 256, 0, stream>>>(
            (const float4*)bxyz, feat, (const bf16x8*)featb, csr_ep, row_start,
            (const bf16x8*)wpack, b1, b2, (const float4*)out_bxyz, out_feat, M);
    else
        agg_kernel<false><<<nblocks, 256, 0, stream>>>(
            (const float4*)bxyz, feat, (const bf16x8*)featb, csr_ep, row_start,
            (const bf16x8*)wpack, b1, b2, (const float4*)out_bxyz, out_feat, M);
}

// Round 6
// 327.528 us; speedup vs baseline: 1.2893x; 1.2700x over previous
//
#include <hip/hip_runtime.h>
#include <hip/hip_bf16.h>

#define CIN 32
#define COUT 64
#define SEGS 2
#define SCHUNK 1024

typedef __attribute__((ext_vector_type(8))) short bf16x8;
typedef __attribute__((ext_vector_type(4))) float f32x4;

__device__ inline short bf16r(float x) {
    unsigned u = __float_as_uint(x);
    return (short)((u + 0x7FFFu + ((u >> 16) & 1u)) >> 16);
}

__device__ inline unsigned pk2(float lo, float hi) {
    __hip_bfloat162 t = __float22bfloat162_rn(make_float2(lo, hi));
    return *(unsigned*)&t;
}

// ---------------------------------------------------------------------------
// Fused prep: [0,32) pack weights | [32,32+nbm) gather bxyz | [.,+nbm) zero
// counts | rest: feat f32 -> bf16 (8 elems/thread).
__global__ void prep_kernel(const float* __restrict__ W1,
                            const float* __restrict__ W2,
                            short* __restrict__ wpack,
                            const float4* __restrict__ bxyz4,
                            const int* __restrict__ sidx,
                            float4* __restrict__ out_bxyz,
                            int* __restrict__ counts,
                            const float* __restrict__ feat,
                            uint4* __restrict__ featb,
                            int M, int N, int nbm) {
    int b = blockIdx.x, tid = threadIdx.x;
    if (b < 32) {
        int t = b * 256 + tid;                 // 8192 exactly
        int e = t & 7, l = (t >> 3) & 63, f = t >> 9;
        int g = l >> 4, n16 = l & 15;
        int kc = (f & 7) >> 2, nt = f & 3;
        int k = kc * 32 + g * 8 + e;
        int n = nt * 16 + n16;
        float v;
        if (f < 8) v = (k < CIN + 3) ? W1[k * COUT + n] : 0.f;
        else       v = W2[k * COUT + n];
        wpack[t] = bf16r(v);
    } else if (b < 32 + nbm) {
        int i = (b - 32) * 256 + tid;
        if (i < M) out_bxyz[i] = bxyz4[sidx[i]];
    } else if (b < 32 + 2 * nbm) {
        int i = (b - 32 - nbm) * 256 + tid;
        if (i < M) counts[i] = 0;
    } else {
        int i = (b - 32 - 2 * nbm) * 256 + tid;   // i indexes 8-float chunks
        if (i < N * (CIN / 8)) {
            const float4* s = (const float4*)feat + (size_t)i * 2;
            float4 a = s[0], c = s[1];
            uint4 o;
            o.x = pk2(a.x, a.y); o.y = pk2(a.z, a.w);
            o.z = pk2(c.x, c.y); o.w = pk2(c.z, c.w);
            featb[i] = o;
        }
    }
}

// ---------------------------------------------------------------------------
// Ticketing: loc[e] = position of edge e within its segment. The histogram's
// atomicAdd return value IS the ticket -> one returning-atomic pass total.
// 8 edges/thread: 8 independent atomics in flight, coalesced int4 loc stores.
__global__ void histloc_kernel(const int4* __restrict__ e_new4,
                               int* __restrict__ counts,
                               int4* __restrict__ loc4, int E8) {
    int i = blockIdx.x * blockDim.x + threadIdx.x;
    if (i >= E8) return;
    int4 a = e_new4[i * 2];
    int4 b = e_new4[i * 2 + 1];
    int4 la, lb;
    la.x = atomicAdd(&counts[a.x], 1);
    la.y = atomicAdd(&counts[a.y], 1);
    la.z = atomicAdd(&counts[a.z], 1);
    la.w = atomicAdd(&counts[a.w], 1);
    lb.x = atomicAdd(&counts[b.x], 1);
    lb.y = atomicAdd(&counts[b.y], 1);
    lb.z = atomicAdd(&counts[b.z], 1);
    lb.w = atomicAdd(&counts[b.w], 1);
    loc4[i * 2]     = la;
    loc4[i * 2 + 1] = lb;
}

// ---------------------------------------------------------------------------
__global__ void scanA_kernel(const int* __restrict__ counts,
                             int* __restrict__ row1,
                             int* __restrict__ sums, int M) {
    __shared__ int lds[256];
    int t = threadIdx.x, blk = blockIdx.x;
    int base = blk * SCHUNK + t * 4;
    int v0 = (base + 0 < M) ? counts[base + 0] : 0;
    int v1 = (base + 1 < M) ? counts[base + 1] : 0;
    int v2 = (base + 2 < M) ? counts[base + 2] : 0;
    int v3 = (base + 3 < M) ? counts[base + 3] : 0;
    int s = v0 + v1 + v2 + v3;
    int val = s;
    lds[t] = val; __syncthreads();
    for (int off = 1; off < 256; off <<= 1) {
        int x = (t >= off) ? lds[t - off] : 0;
        __syncthreads();
        val += x; lds[t] = val;
        __syncthreads();
    }
    int ex = val - s;
    if (base + 0 < M) row1[base + 0] = ex + v0;
    if (base + 1 < M) row1[base + 1] = ex + v0 + v1;
    if (base + 2 < M) row1[base + 2] = ex + v0 + v1 + v2;
    if (base + 3 < M) row1[base + 3] = ex + s;
    if (t == 255) sums[blk] = val;
}

__global__ void scanB_kernel(int* __restrict__ sums, int n) {
    __shared__ int lds[256];
    int t = threadIdx.x;
    int s = (t < n) ? sums[t] : 0;
    int val = s;
    lds[t] = val; __syncthreads();
    for (int off = 1; off < 256; off <<= 1) {
        int x = (t >= off) ? lds[t - off] : 0;
        __syncthreads();
        val += x; lds[t] = val;
        __syncthreads();
    }
    if (t < n) sums[t] = val;
}

__global__ void scanC_kernel(int* __restrict__ row1,
                             const int* __restrict__ sums,
                             int* __restrict__ row_start, int M) {
    int blk = blockIdx.x, t = threadIdx.x;
    if (blk == 0) {
        if (t == 0) row_start[0] = 0;
        return;
    }
    int off = sums[blk - 1];
    int base = blk * SCHUNK + t * 4;
#pragma unroll
    for (int i = 0; i < 4; ++i)
        if (base + i < M) row1[base + i] += off;
}

// ---------------------------------------------------------------------------
// Placement: NO atomics. All reads coalesced (row_start gather is L2-hit,
// 500 KB); scattered 4B stores are fire-and-forget.
__global__ void place_kernel(const int4* __restrict__ e_new4,
                             const int4* __restrict__ e_point4,
                             const int4* __restrict__ loc4,
                             const int* __restrict__ row_start,
                             int* __restrict__ csr_ep, int E8) {
    int i = blockIdx.x * blockDim.x + threadIdx.x;
    if (i >= E8) return;
    int4 n0 = e_new4[i * 2],   n1 = e_new4[i * 2 + 1];
    int4 p0 = e_point4[i * 2], p1 = e_point4[i * 2 + 1];
    int4 l0 = loc4[i * 2],     l1 = loc4[i * 2 + 1];
    csr_ep[row_start[n0.x] + l0.x] = p0.x;
    csr_ep[row_start[n0.y] + l0.y] = p0.y;
    csr_ep[row_start[n0.z] + l0.z] = p0.z;
    csr_ep[row_start[n0.w] + l0.w] = p0.w;
    csr_ep[row_start[n1.x] + l1.x] = p1.x;
    csr_ep[row_start[n1.y] + l1.y] = p1.y;
    csr_ep[row_start[n1.z] + l1.z] = p1.z;
    csr_ep[row_start[n1.w] + l1.w] = p1.w;
}

// ---------------------------------------------------------------------------
// Aggregation: wave = segment (SEGS per wave). MFMA MLP, f32 LDS transpose
// with XOR swizzle + cvt_pk on read, in-register max, coalesced row store.
template <bool BF>
__global__ __launch_bounds__(256)
void agg_kernel(const float4* __restrict__ bxyz4,
                const float* __restrict__ feat,
                const bf16x8* __restrict__ featb,
                const int* __restrict__ csr_ep,
                const int* __restrict__ row_start,
                const bf16x8* __restrict__ wpack,
                const float* __restrict__ b1,
                const float* __restrict__ b2,
                const float4* __restrict__ new_bxyz4,
                float* __restrict__ out_feat, int M) {
    __shared__ char h1buf[4][4096];   // wave-private 16x64 f32, swizzled
    const int lane = threadIdx.x & 63;
    const int w    = threadIdx.x >> 6;
    const int m    = lane & 15;
    const int g    = lane >> 4;

    bf16x8 w1b[8], w2b[8];
#pragma unroll
    for (int f = 0; f < 8; ++f) w1b[f] = wpack[f * 64 + lane];
#pragma unroll
    for (int f = 0; f < 8; ++f) w2b[f] = wpack[(8 + f) * 64 + lane];

    float b1v[4], b2v[4];
#pragma unroll
    for (int nt = 0; nt < 4; ++nt) {
        b1v[nt] = b1[nt * 16 + m];
        b2v[nt] = b2[nt * 16 + m];
    }

    char* h1p = h1buf[w];
    int segbase = (blockIdx.x * 4 + w) * SEGS;

    for (int s = 0; s < SEGS; ++s) {
        int seg = segbase + s;                 // wave-uniform
        if (seg >= M) break;
        int r0 = row_start[seg];
        int r1 = row_start[seg + 1];
        float4 nb = new_bxyz4[seg];

        f32x4 accv = {0.f, 0.f, 0.f, 0.f};    // relu floor == empty-seg value

        for (int c = r0; c < r1; c += 16) {
            int i = min(c + m, r1 - 1);        // clamp: dup edges, max-safe
            int ep = csr_ep[i];

            bf16x8 a1;
            if constexpr (BF) {
                a1 = featb[(size_t)ep * 4 + g];          // one dwordx4
            } else {
                const float4* fp = (const float4*)(feat + (size_t)ep * CIN);
                float4 f0 = fp[g * 2];
                float4 f1 = fp[g * 2 + 1];
                union { bf16x8 v; unsigned u[4]; } U;
                U.u[0] = pk2(f0.x, f0.y); U.u[1] = pk2(f0.z, f0.w);
                U.u[2] = pk2(f1.x, f1.y); U.u[3] = pk2(f1.z, f1.w);
                a1 = U.v;
            }

            bf16x8 a2 = {0, 0, 0, 0, 0, 0, 0, 0};
            if (g == 0) {
                float4 pb = bxyz4[ep];
                a2[0] = bf16r(pb.y - nb.y);
                a2[1] = bf16r(pb.z - nb.z);
                a2[2] = bf16r(pb.w - nb.w);
            }

            // ---- layer 1 --------------------------------------------------
            f32x4 acc[4];
#pragma unroll
            for (int nt = 0; nt < 4; ++nt) {
                f32x4 cc = {b1v[nt], b1v[nt], b1v[nt], b1v[nt]};
                cc = __builtin_amdgcn_mfma_f32_16x16x32_bf16(a1, w1b[nt],     cc, 0, 0, 0);
                cc = __builtin_amdgcn_mfma_f32_16x16x32_bf16(a2, w1b[4 + nt], cc, 0, 0, 0);
                acc[nt] = cc;
            }

            // ---- relu + f32 transpose through wave-private LDS ------------
#pragma unroll
            for (int nt = 0; nt < 4; ++nt)
#pragma unroll
                for (int q = 0; q < 4; ++q) {
                    int row = g * 4 + q;
                    int col = m + nt * 16;
                    float h = fmaxf(acc[nt][q], 0.f);
                    int byte = (row * 256 + col * 4) ^ ((row & 7) << 5);
                    *(float*)(h1p + byte) = h;
                }

            const int key = (m & 7) << 5;
            float4 q0 = *(const float4*)(h1p + ((m * 256 + g * 32)        ^ key));
            float4 q1 = *(const float4*)(h1p + ((m * 256 + g * 32 + 16)   ^ key));
            float4 q2 = *(const float4*)(h1p + ((m * 256 + 128 + g * 32)      ^ key));
            float4 q3 = *(const float4*)(h1p + ((m * 256 + 128 + g * 32 + 16) ^ key));

            union { bf16x8 v; unsigned u[4]; } A30, A31;
            A30.u[0] = pk2(q0.x, q0.y); A30.u[1] = pk2(q0.z, q0.w);
            A30.u[2] = pk2(q1.x, q1.y); A30.u[3] = pk2(q1.z, q1.w);
            A31.u[0] = pk2(q2.x, q2.y); A31.u[1] = pk2(q2.z, q2.w);
            A31.u[2] = pk2(q3.x, q3.y); A31.u[3] = pk2(q3.z, q3.w);

            // ---- layer 2 --------------------------------------------------
            f32x4 acc2[4];
#pragma unroll
            for (int nt = 0; nt < 4; ++nt) {
                f32x4 cc = {b2v[nt], b2v[nt], b2v[nt], b2v[nt]};
                cc = __builtin_amdgcn_mfma_f32_16x16x32_bf16(A30.v, w2b[nt],     cc, 0, 0, 0);
                cc = __builtin_amdgcn_mfma_f32_16x16x32_bf16(A31.v, w2b[4 + nt], cc, 0, 0, 0);
                acc2[nt] = cc;
            }

#pragma unroll
            for (int nt = 0; nt < 4; ++nt) {
                f32x4 c2 = acc2[nt];
                float t = fmaxf(fmaxf(c2[0], c2[1]), fmaxf(c2[2], c2[3]));
                accv[nt] = fmaxf(accv[nt], t);
            }
        }

        // ---- max across row-groups + coalesced store ----------------------
#pragma unroll
        for (int nt = 0; nt < 4; ++nt) {
            float v = accv[nt];
            v = fmaxf(v, __shfl_xor(v, 16));
            v = fmaxf(v, __shfl_xor(v, 32));
            accv[nt] = v;
        }
        float outv = (g == 0) ? accv[0] : (g == 1) ? accv[1]
                   : (g == 2) ? accv[2] : accv[3];
        out_feat[(size_t)seg * COUT + lane] = outv;
    }
}

// ---------------------------------------------------------------------------
extern "C" void kernel_launch(void* const* d_in, const int* in_sizes, int n_in,
                              void* d_out, int out_size, void* d_ws, size_t ws_size,
                              hipStream_t stream) {
    const float* bxyz   = (const float*)d_in[0];
    const float* feat   = (const float*)d_in[1];
    const int*   sidx   = (const int*)d_in[2];
    const int*   e_pt   = (const int*)d_in[3];
    const int*   e_new  = (const int*)d_in[4];
    const float* W1     = (const float*)d_in[5];
    const float* b1     = (const float*)d_in[6];
    const float* W2     = (const float*)d_in[7];
    const float* b2     = (const float*)d_in[8];

    const int N = in_sizes[0] / 4;
    const int M = in_sizes[2];
    const int E = in_sizes[3];

    float* out_bxyz = (float*)d_out;                 // [M][4]
    float* out_feat = out_bxyz + (size_t)M * 4;      // [M][64]

    // ws layout (16B aligned regions)
    char*  ws        = (char*)d_ws;
    short* wpack     = (short*)ws;                                    // 16 KiB
    size_t off_cnt   = 16384;
    int*   counts    = (int*)(ws + off_cnt);                          // M
    size_t off_row   = off_cnt + (((size_t)M * 4 + 15) & ~(size_t)15);
    int*   row_start = (int*)(ws + off_row);                          // M+4
    size_t off_sums  = off_row + ((((size_t)M + 4) * 4 + 15) & ~(size_t)15);
    int*   sums      = (int*)(ws + off_sums);                         // 256
    size_t off_loc   = off_sums + 1024;
    int*   loc       = (int*)(ws + off_loc);                          // E
    size_t off_csr   = off_loc + (size_t)E * 4;
    int*   csr_ep    = (int*)(ws + off_csr);                          // E
    size_t off_fb    = (off_csr + (size_t)E * 4 + 15) & ~(size_t)15;
    uint4* featb     = (uint4*)(ws + off_fb);                         // N*64B
    size_t need_bf   = off_fb + (size_t)N * CIN * 2;
    int*   row1      = row_start + 1;

    const bool use_bf = ws_size >= need_bf;

    int nbm     = (M + 255) / 256;
    int nbfeat  = use_bf ? (N * (CIN / 8) + 255) / 256 : 0;
    int nchunks = (M + SCHUNK - 1) / SCHUNK;
    int E8      = E / 8;   // E divisible by 8 here

    prep_kernel<<<32 + 2 * nbm + nbfeat, 256, 0, stream>>>(
        W1, W2, wpack, (const float4*)bxyz, sidx, (float4*)out_bxyz,
        counts, feat, featb, M, N, nbm);

    histloc_kernel<<<(E8 + 255) / 256, 256, 0, stream>>>(
        (const int4*)e_new, counts, (int4*)loc, E8);
    scanA_kernel<<<nchunks, 256, 0, stream>>>(counts, row1, sums, M);
    scanB_kernel<<<1, 256, 0, stream>>>(sums, nchunks);
    scanC_kernel<<<nchunks, 256, 0, stream>>>(row1, sums, row_start, M);
    place_kernel<<<(E8 + 255) / 256, 256, 0, stream>>>(
        (const int4*)e_new, (const int4*)e_pt, (const int4*)loc,
        row_start, csr_ep, E8);

    int nblocks = (M + SEGS * 4 - 1) / (SEGS * 4);
    if (use_bf)
        agg_kernel<true><<<nblocks, 256, 0, stream>>>(
            (const float4*)bxyz, feat, (const bf16x8*)featb, csr_ep, row_start,
            (const bf16x8*)wpack, b1, b2, (const float4*)out_bxyz, out_feat, M);
    else
        agg_kernel<false><<<nblocks, 256, 0, stream>>>(
            (const float4*)bxyz, feat, (const bf16x8*)featb, csr_ep, row_start,
            (const bf16x8*)wpack, b1, b2, (const float4*)out_bxyz, out_feat, M);
}

// Round 7
// 289.687 us; speedup vs baseline: 1.4577x; 1.1306x over previous
//
#include <hip/hip_runtime.h>
#include <hip/hip_bf16.h>

#define CIN 32
#define COUT 64
#define SEGS 8
#define SCHUNK 1024

typedef __attribute__((ext_vector_type(8))) short bf16x8;
typedef __attribute__((ext_vector_type(4))) float f32x4;

__device__ inline short bf16r(float x) {
    unsigned u = __float_as_uint(x);
    return (short)((u + 0x7FFFu + ((u >> 16) & 1u)) >> 16);
}

__device__ inline unsigned pk2(float lo, float hi) {
    __hip_bfloat162 t = __float22bfloat162_rn(make_float2(lo, hi));
    return *(unsigned*)&t;
}

// ---------------------------------------------------------------------------
// Fused prep: [0,32) pack weights | [32,32+nbm) gather out_bxyz | [+nbm) zero
// counts | rest: build 80B featb rows = 32 bf16 feats + bf16 pb.xyz + pad.
__global__ void prep_kernel(const float* __restrict__ W1,
                            const float* __restrict__ W2,
                            short* __restrict__ wpack,
                            const float4* __restrict__ bxyz4,
                            const int* __restrict__ sidx,
                            float4* __restrict__ out_bxyz,
                            int* __restrict__ counts,
                            const float* __restrict__ feat,
                            uint4* __restrict__ featb,
                            int M, int N, int nbm) {
    int b = blockIdx.x, tid = threadIdx.x;
    if (b < 32) {
        int t = b * 256 + tid;                 // 8192 exactly
        int e = t & 7, l = (t >> 3) & 63, f = t >> 9;
        int g = l >> 4, n16 = l & 15;
        int kc = (f & 7) >> 2, nt = f & 3;
        int k = kc * 32 + g * 8 + e;
        int n = nt * 16 + n16;
        float v;
        if (f < 8) v = (k < CIN + 3) ? W1[k * COUT + n] : 0.f;
        else       v = W2[k * COUT + n];
        wpack[t] = bf16r(v);
    } else if (b < 32 + nbm) {
        int i = (b - 32) * 256 + tid;
        if (i < M) out_bxyz[i] = bxyz4[sidx[i]];
    } else if (b < 32 + 2 * nbm) {
        int i = (b - 32 - nbm) * 256 + tid;
        if (i < M) counts[i] = 0;
    } else {
        int p = (b - 32 - 2 * nbm) * 256 + tid;
        if (p < N) {
            const float4* s = (const float4*)(feat + (size_t)p * CIN);
            float4 f0 = s[0], f1 = s[1], f2 = s[2], f3 = s[3];
            float4 f4 = s[4], f5 = s[5], f6 = s[6], f7 = s[7];
            float4 pb = bxyz4[p];
            uint4* d = featb + (size_t)p * 5;
            d[0] = make_uint4(pk2(f0.x, f0.y), pk2(f0.z, f0.w), pk2(f1.x, f1.y), pk2(f1.z, f1.w));
            d[1] = make_uint4(pk2(f2.x, f2.y), pk2(f2.z, f2.w), pk2(f3.x, f3.y), pk2(f3.z, f3.w));
            d[2] = make_uint4(pk2(f4.x, f4.y), pk2(f4.z, f4.w), pk2(f5.x, f5.y), pk2(f5.z, f5.w));
            d[3] = make_uint4(pk2(f6.x, f6.y), pk2(f6.z, f6.w), pk2(f7.x, f7.y), pk2(f7.z, f7.w));
            d[4] = make_uint4(pk2(pb.y, pb.z), pk2(pb.w, 0.f), 0u, 0u);
        }
    }
}

// ---------------------------------------------------------------------------
// Ticketing: one returning-atomic pass; loc[e] = within-segment position.
__global__ void histloc_kernel(const int4* __restrict__ e_new4,
                               int* __restrict__ counts,
                               int4* __restrict__ loc4, int E8) {
    int i = blockIdx.x * blockDim.x + threadIdx.x;
    if (i >= E8) return;
    int4 a = e_new4[i * 2];
    int4 b = e_new4[i * 2 + 1];
    int4 la, lb;
    la.x = atomicAdd(&counts[a.x], 1);
    la.y = atomicAdd(&counts[a.y], 1);
    la.z = atomicAdd(&counts[a.z], 1);
    la.w = atomicAdd(&counts[a.w], 1);
    lb.x = atomicAdd(&counts[b.x], 1);
    lb.y = atomicAdd(&counts[b.y], 1);
    lb.z = atomicAdd(&counts[b.z], 1);
    lb.w = atomicAdd(&counts[b.w], 1);
    loc4[i * 2]     = la;
    loc4[i * 2 + 1] = lb;
}

// ---------------------------------------------------------------------------
__global__ void scanA_kernel(const int* __restrict__ counts,
                             int* __restrict__ row1,
                             int* __restrict__ sums, int M) {
    __shared__ int lds[256];
    int t = threadIdx.x, blk = blockIdx.x;
    int base = blk * SCHUNK + t * 4;
    int v0 = (base + 0 < M) ? counts[base + 0] : 0;
    int v1 = (base + 1 < M) ? counts[base + 1] : 0;
    int v2 = (base + 2 < M) ? counts[base + 2] : 0;
    int v3 = (base + 3 < M) ? counts[base + 3] : 0;
    int s = v0 + v1 + v2 + v3;
    int val = s;
    lds[t] = val; __syncthreads();
    for (int off = 1; off < 256; off <<= 1) {
        int x = (t >= off) ? lds[t - off] : 0;
        __syncthreads();
        val += x; lds[t] = val;
        __syncthreads();
    }
    int ex = val - s;
    if (base + 0 < M) row1[base + 0] = ex + v0;
    if (base + 1 < M) row1[base + 1] = ex + v0 + v1;
    if (base + 2 < M) row1[base + 2] = ex + v0 + v1 + v2;
    if (base + 3 < M) row1[base + 3] = ex + s;
    if (t == 255) sums[blk] = val;
}

__global__ void scanB_kernel(int* __restrict__ sums, int n) {
    __shared__ int lds[256];
    int t = threadIdx.x;
    int s = (t < n) ? sums[t] : 0;
    int val = s;
    lds[t] = val; __syncthreads();
    for (int off = 1; off < 256; off <<= 1) {
        int x = (t >= off) ? lds[t - off] : 0;
        __syncthreads();
        val += x; lds[t] = val;
        __syncthreads();
    }
    if (t < n) sums[t] = val;
}

__global__ void scanC_kernel(int* __restrict__ row1,
                             const int* __restrict__ sums,
                             int* __restrict__ row_start, int M) {
    int blk = blockIdx.x, t = threadIdx.x;
    if (blk == 0) {
        if (t == 0) row_start[0] = 0;
        return;
    }
    int off = sums[blk - 1];
    int base = blk * SCHUNK + t * 4;
#pragma unroll
    for (int i = 0; i < 4; ++i)
        if (base + i < M) row1[base + i] += off;
}

// ---------------------------------------------------------------------------
__global__ void place_kernel(const int4* __restrict__ e_new4,
                             const int4* __restrict__ e_point4,
                             const int4* __restrict__ loc4,
                             const int* __restrict__ row_start,
                             int* __restrict__ csr_ep, int E8) {
    int i = blockIdx.x * blockDim.x + threadIdx.x;
    if (i >= E8) return;
    int4 n0 = e_new4[i * 2],   n1 = e_new4[i * 2 + 1];
    int4 p0 = e_point4[i * 2], p1 = e_point4[i * 2 + 1];
    int4 l0 = loc4[i * 2],     l1 = loc4[i * 2 + 1];
    csr_ep[row_start[n0.x] + l0.x] = p0.x;
    csr_ep[row_start[n0.y] + l0.y] = p0.y;
    csr_ep[row_start[n0.z] + l0.z] = p0.z;
    csr_ep[row_start[n0.w] + l0.w] = p0.w;
    csr_ep[row_start[n1.x] + l1.x] = p1.x;
    csr_ep[row_start[n1.y] + l1.y] = p1.y;
    csr_ep[row_start[n1.z] + l1.z] = p1.z;
    csr_ep[row_start[n1.w] + l1.w] = p1.w;
}

// ---------------------------------------------------------------------------
// Aggregation: wave = segment stream (SEGS segments), 3-slot software pipeline
// (featb gathers 2 phases in flight). LDS transpose swizzle derived for 2-way
// writes (free) and optimal 8-lanes/granule b128 reads.
// Per-segment rel trick: h1 = [feat|pb]·W1 + (b1 - nb·W1r)  (nb folded to bias).
__global__ __launch_bounds__(256)
void agg_kernel(const uint4* __restrict__ featb,     // [N][5] 16B chunks
                const int* __restrict__ csr_ep,
                const int* __restrict__ row_start,
                const bf16x8* __restrict__ wpack,
                const float* __restrict__ b1,
                const float* __restrict__ b2,
                const float* __restrict__ W1,
                const float4* __restrict__ new_bxyz4,
                float* __restrict__ out_feat, int M) {
    __shared__ char h1buf[4][4096];   // wave-private 16x64 f32, swizzled
    const int lane = threadIdx.x & 63;
    const int w    = threadIdx.x >> 6;
    const int m    = lane & 15;
    const int g    = lane >> 4;

    int segbase = (blockIdx.x * 4 + w) * SEGS;
    if (segbase >= M) return;
    int segend = min(segbase + SEGS, M);

    bf16x8 w1b[8], w2b[8];
#pragma unroll
    for (int f = 0; f < 8; ++f) w1b[f] = wpack[f * 64 + lane];
#pragma unroll
    for (int f = 0; f < 8; ++f) w2b[f] = wpack[(8 + f) * 64 + lane];

    float b1v[4], b2v[4], w1r0[4], w1r1[4], w1r2[4];
#pragma unroll
    for (int nt = 0; nt < 4; ++nt) {
        int col = nt * 16 + m;
        b1v[nt]  = b1[col];
        b2v[nt]  = b2[col];
        w1r0[nt] = W1[32 * COUT + col];
        w1r1[nt] = W1[33 * COUT + col];
        w1r2[nt] = W1[34 * COUT + col];
    }

    char* h1p = h1buf[w];
    const int kk2 = ((m & 3) << 5) | ((m & 4) << 2) | ((m & 8) << 3);

    // ---- cursor (wave-uniform) -------------------------------------------
    int  seg = segbase - 1;
    bool curval = true;
    bool lastF = false;
    int  r1 = row_start[segbase];
    int  c  = r1;
    int  r2 = row_start[min(segbase + 1, M)];

    auto advance = [&]() {
        c += 16;
        while (c >= r1) {
            ++seg;
            if (seg >= segend) { curval = false; return; }
            c = r1; r1 = r2;
            r2 = row_start[min(seg + 2, M)];
            if (c < r1) break;
            out_feat[(size_t)seg * COUT + lane] = 0.f;   // empty segment
        }
        lastF = (c + 16 >= r1);
    };

    f32x4 accv = {0.f, 0.f, 0.f, 0.f};

#define TILE_COMPUTE(A1, C4X, C4Y, NB, SEGV, LASTV)                           \
    do {                                                                      \
        bf16x8 a2 = {0, 0, 0, 0, 0, 0, 0, 0};                                 \
        if (g == 0) {                                                         \
            a2[0] = (short)(C4X & 0xffffu);                                   \
            a2[1] = (short)(C4X >> 16);                                       \
            a2[2] = (short)(C4Y & 0xffffu);                                   \
        }                                                                     \
        f32x4 acc[4];                                                         \
        _Pragma("unroll")                                                     \
        for (int nt = 0; nt < 4; ++nt) {                                      \
            float be = b1v[nt] - NB.y * w1r0[nt] - NB.z * w1r1[nt]            \
                                - NB.w * w1r2[nt];                            \
            f32x4 cc = {be, be, be, be};                                      \
            cc = __builtin_amdgcn_mfma_f32_16x16x32_bf16(A1, w1b[nt], cc, 0, 0, 0); \
            cc = __builtin_amdgcn_mfma_f32_16x16x32_bf16(a2, w1b[4 + nt], cc, 0, 0, 0); \
            acc[nt] = cc;                                                     \
        }                                                                     \
        _Pragma("unroll")                                                     \
        for (int nt = 0; nt < 4; ++nt)                                        \
            _Pragma("unroll")                                                 \
            for (int q = 0; q < 4; ++q) {                                     \
                int row = g * 4 + q;                                          \
                int col = m + nt * 16;                                        \
                float h = fmaxf(acc[nt][q], 0.f);                             \
                int kk = ((row & 3) << 5) | ((row & 4) << 2) | ((row & 8) << 3); \
                *(float*)(h1p + ((row * 256 + col * 4) ^ kk)) = h;            \
            }                                                                 \
        float4 q0 = *(const float4*)(h1p + ((m * 256 + g * 32      ) ^ kk2)); \
        float4 q1 = *(const float4*)(h1p + ((m * 256 + g * 32 + 16 ) ^ kk2)); \
        float4 q2 = *(const float4*)(h1p + ((m * 256 + g * 32 + 128) ^ kk2)); \
        float4 q3 = *(const float4*)(h1p + ((m * 256 + g * 32 + 144) ^ kk2)); \
        union { bf16x8 v; unsigned u[4]; } A30, A31;                          \
        A30.u[0] = pk2(q0.x, q0.y); A30.u[1] = pk2(q0.z, q0.w);               \
        A30.u[2] = pk2(q1.x, q1.y); A30.u[3] = pk2(q1.z, q1.w);               \
        A31.u[0] = pk2(q2.x, q2.y); A31.u[1] = pk2(q2.z, q2.w);               \
        A31.u[2] = pk2(q3.x, q3.y); A31.u[3] = pk2(q3.z, q3.w);               \
        _Pragma("unroll")                                                     \
        for (int nt = 0; nt < 4; ++nt) {                                      \
            f32x4 cc = {b2v[nt], b2v[nt], b2v[nt], b2v[nt]};                  \
            cc = __builtin_amdgcn_mfma_f32_16x16x32_bf16(A30.v, w2b[nt], cc, 0, 0, 0); \
            cc = __builtin_amdgcn_mfma_f32_16x16x32_bf16(A31.v, w2b[4 + nt], cc, 0, 0, 0); \
            float t = fmaxf(fmaxf(cc[0], cc[1]), fmaxf(cc[2], cc[3]));        \
            accv[nt] = fmaxf(accv[nt], t);                                    \
        }                                                                     \
        if (LASTV) {                                                          \
            _Pragma("unroll")                                                 \
            for (int nt = 0; nt < 4; ++nt) {                                  \
                float v = accv[nt];                                           \
                v = fmaxf(v, __shfl_xor(v, 16));                              \
                v = fmaxf(v, __shfl_xor(v, 32));                              \
                accv[nt] = v;                                                 \
            }                                                                 \
            float outv = (g == 0) ? accv[0] : (g == 1) ? accv[1]              \
                       : (g == 2) ? accv[2] : accv[3];                        \
            out_feat[(size_t)SEGV * COUT + lane] = outv;                      \
            accv[0] = accv[1] = accv[2] = accv[3] = 0.f;                      \
        }                                                                     \
    } while (0)

    // ---- pipeline slots ---------------------------------------------------
    bf16x8 a10, a11, a12;
    unsigned c4x0 = 0, c4y0 = 0, c4x1 = 0, c4y1 = 0, c4x2 = 0, c4y2 = 0;
    int ep0, ep1, ep2;
    int seg0, seg1, seg2;
    bool last0, last1, last2, valid0, valid1, valid2;
    float4 nb0, nb1, nb2;

    advance();
    seg0 = seg; last0 = lastF; valid0 = curval;
    { int iE = valid0 ? min(c + m, r1 - 1) : 0;
      ep0 = csr_ep[iE];
      nb0 = new_bxyz4[valid0 ? min(seg0, M - 1) : 0]; }
    advance();
    seg1 = seg; last1 = lastF; valid1 = curval;
    { int iE = valid1 ? min(c + m, r1 - 1) : 0;
      ep1 = csr_ep[iE];
      nb1 = new_bxyz4[valid1 ? min(seg1, M - 1) : 0]; }
    advance();
    seg2 = seg; last2 = lastF; valid2 = curval;
    { int iE = valid2 ? min(c + m, r1 - 1) : 0;
      ep2 = csr_ep[iE];
      nb2 = new_bxyz4[valid2 ? min(seg2, M - 1) : 0]; }

    {   // prologue featb for slots 0,1
        const uint4* fr = featb + (size_t)(unsigned)ep0 * 5;
        a10 = ((const bf16x8*)fr)[g];
        uint2 t4 = *(const uint2*)(fr + 4); c4x0 = t4.x; c4y0 = t4.y;
    }
    {
        const uint4* fr = featb + (size_t)(unsigned)ep1 * 5;
        a11 = ((const bf16x8*)fr)[g];
        uint2 t4 = *(const uint2*)(fr + 4); c4x1 = t4.x; c4y1 = t4.y;
    }

#define PHASE(I0, I1, I2)                                                     \
    if (!valid##I0) break;                                                    \
    {   /* featb issue for stage p+2 (slot I2) */                             \
        const uint4* fr = featb + (size_t)(unsigned)ep##I2 * 5;               \
        a1##I2 = ((const bf16x8*)fr)[g];                                      \
        uint2 t4 = *(const uint2*)(fr + 4);                                   \
        c4x##I2 = t4.x; c4y##I2 = t4.y;                                       \
    }                                                                         \
    advance();                                                                \
    {   int tseg = seg; bool tlast = lastF, tval = curval;                    \
        int iE = tval ? min(c + m, r1 - 1) : 0;                               \
        ep##I0 = csr_ep[iE];                   /* stage p+3 into freed slot */\
        TILE_COMPUTE(a1##I0, c4x##I0, c4y##I0, nb##I0, seg##I0, last##I0);    \
        seg##I0 = tseg; last##I0 = tlast; valid##I0 = tval;                   \
        nb##I0 = new_bxyz4[tval ? min(tseg, M - 1) : 0];                      \
    }

    for (;;) {
        PHASE(0, 1, 2)
        PHASE(1, 2, 0)
        PHASE(2, 0, 1)
    }
#undef PHASE
#undef TILE_COMPUTE
}

// ---------------------------------------------------------------------------
extern "C" void kernel_launch(void* const* d_in, const int* in_sizes, int n_in,
                              void* d_out, int out_size, void* d_ws, size_t ws_size,
                              hipStream_t stream) {
    const float* bxyz   = (const float*)d_in[0];
    const float* feat   = (const float*)d_in[1];
    const int*   sidx   = (const int*)d_in[2];
    const int*   e_pt   = (const int*)d_in[3];
    const int*   e_new  = (const int*)d_in[4];
    const float* W1     = (const float*)d_in[5];
    const float* b1     = (const float*)d_in[6];
    const float* W2     = (const float*)d_in[7];
    const float* b2     = (const float*)d_in[8];

    const int N = in_sizes[0] / 4;
    const int M = in_sizes[2];
    const int E = in_sizes[3];

    float* out_bxyz = (float*)d_out;                 // [M][4]
    float* out_feat = out_bxyz + (size_t)M * 4;      // [M][64]

    // ws layout (16B aligned regions)
    char*  ws        = (char*)d_ws;
    short* wpack     = (short*)ws;                                    // 16 KiB
    size_t off_cnt   = 16384;
    int*   counts    = (int*)(ws + off_cnt);                          // M
    size_t off_row   = off_cnt + (((size_t)M * 4 + 15) & ~(size_t)15);
    int*   row_start = (int*)(ws + off_row);                          // M+4
    size_t off_sums  = off_row + ((((size_t)M + 4) * 4 + 15) & ~(size_t)15);
    int*   sums      = (int*)(ws + off_sums);                         // 256
    size_t off_loc   = off_sums + 1024;
    int*   loc       = (int*)(ws + off_loc);                          // E
    size_t off_csr   = off_loc + (size_t)E * 4;
    int*   csr_ep    = (int*)(ws + off_csr);                          // E
    size_t off_fb    = (off_csr + (size_t)E * 4 + 15) & ~(size_t)15;
    uint4* featb     = (uint4*)(ws + off_fb);                         // N*80B
    int*   row1      = row_start + 1;

    int nbm     = (M + 255) / 256;
    int nbp     = (N + 255) / 256;
    int nchunks = (M + SCHUNK - 1) / SCHUNK;
    int E8      = E / 8;   // E divisible by 8 here

    prep_kernel<<<32 + 2 * nbm + nbp, 256, 0, stream>>>(
        W1, W2, wpack, (const float4*)bxyz, sidx, (float4*)out_bxyz,
        counts, feat, featb, M, N, nbm);

    histloc_kernel<<<(E8 + 255) / 256, 256, 0, stream>>>(
        (const int4*)e_new, counts, (int4*)loc, E8);
    scanA_kernel<<<nchunks, 256, 0, stream>>>(counts, row1, sums, M);
    scanB_kernel<<<1, 256, 0, stream>>>(sums, nchunks);
    scanC_kernel<<<nchunks, 256, 0, stream>>>(row1, sums, row_start, M);
    place_kernel<<<(E8 + 255) / 256, 256, 0, stream>>>(
        (const int4*)e_new, (const int4*)e_pt, (const int4*)loc,
        row_start, csr_ep, E8);

    int nblocks = (M + 4 * SEGS - 1) / (4 * SEGS);
    agg_kernel<<<nblocks, 256, 0, stream>>>(
        featb, csr_ep, row_start, (const bf16x8*)wpack,
        b1, b2, W1, (const float4*)out_bxyz, out_feat, M);
}